// Round 8
// baseline (481.496 us; speedup 1.0000x reference)
//
#include <hip/hip_runtime.h>
#include <hip/hip_bf16.h>

#define EPSB 1e-5f

typedef __hip_bfloat16 bf16;
typedef __attribute__((ext_vector_type(8))) short bf16x8;
typedef __attribute__((ext_vector_type(4))) float f32x4;

typedef union { uint4 u; bf16x8 h; } u4h8;

__device__ __forceinline__ unsigned short f2bu(float x) {
  bf16 h = __float2bfloat16(x);
  return *reinterpret_cast<unsigned short*>(&h);
}
__device__ __forceinline__ unsigned int pk2(float lo, float hi) {
  return ((unsigned int)f2bu(hi) << 16) | (unsigned int)f2bu(lo);
}

// ------------------------- fused (sub|x) grouped 3x3 conv, tiled, bf16 output
__global__ __launch_bounds__(256) void k_dwconv2(
    const float* __restrict__ x1, const float* __restrict__ x2,
    const float* __restrict__ xs, const float* __restrict__ w,
    const float* __restrict__ bias, bf16* __restrict__ h) {
  __shared__ float img[2 * 64 * 64];
  int g = blockIdx.x, b = blockIdx.y;
  int t = threadIdx.x;

  if (g < 128) {
    const float4* p1 = (const float4*)(x1 + ((size_t)(b * 256 + 2 * g) << 12));
    const float4* p2 = (const float4*)(x2 + ((size_t)(b * 256 + 2 * g) << 12));
#pragma unroll
    for (int u = 0; u < 8; u++) {
      int i = u * 256 + t;
      float4 a = p1[i], c = p2[i];
      float4 d = {a.x - c.x, a.y - c.y, a.z - c.z, a.w - c.w};
      ((float4*)img)[i] = d;
    }
  } else {
    const float4* p1 = (const float4*)(xs + ((size_t)(b * 256 + 2 * (g - 128)) << 12));
#pragma unroll
    for (int u = 0; u < 8; u++) {
      int i = u * 256 + t;
      ((float4*)img)[i] = p1[i];
    }
  }
  __syncthreads();

  int row = t >> 2, x0 = (t & 3) * 16;
  const float* wp = w + (size_t)(2 * g) * 18;
  float o0[16], o1[16];
  float bs0 = bias[2 * g], bs1 = bias[2 * g + 1];
#pragma unroll
  for (int i = 0; i < 16; i++) { o0[i] = bs0; o1[i] = bs1; }

#pragma unroll
  for (int ch = 0; ch < 2; ch++) {
    float wa[9], wb[9];
#pragma unroll
    for (int i = 0; i < 9; i++) { wa[i] = wp[ch * 9 + i]; wb[i] = wp[18 + ch * 9 + i]; }
    const float* ib = img + ch * 4096;
#pragma unroll
    for (int ky = 0; ky < 3; ky++) {
      int yy = row + ky - 1;
      if (yy < 0 || yy > 63) continue;
      float v[18];
#pragma unroll
      for (int c = 0; c < 18; c++) {
        int xx = x0 + c - 1;
        v[c] = (xx >= 0 && xx < 64) ? ib[yy * 64 + xx] : 0.f;
      }
      float a0 = wa[ky * 3], a1 = wa[ky * 3 + 1], a2 = wa[ky * 3 + 2];
      float c0 = wb[ky * 3], c1 = wb[ky * 3 + 1], c2 = wb[ky * 3 + 2];
#pragma unroll
      for (int i = 0; i < 16; i++) {
        o0[i] += a0 * v[i] + a1 * v[i + 1] + a2 * v[i + 2];
        o1[i] += c0 * v[i] + c1 * v[i + 1] + c2 * v[i + 2];
      }
    }
  }

  size_t base = (((size_t)(b * 512 + 2 * g)) << 12) + row * 64 + x0;
  uint4 u0 = {pk2(o0[0], o0[1]), pk2(o0[2], o0[3]), pk2(o0[4], o0[5]), pk2(o0[6], o0[7])};
  uint4 u1 = {pk2(o0[8], o0[9]), pk2(o0[10], o0[11]), pk2(o0[12], o0[13]), pk2(o0[14], o0[15])};
  *(uint4*)&h[base] = u0;
  *(uint4*)&h[base + 8] = u1;
  uint4 w0 = {pk2(o1[0], o1[1]), pk2(o1[2], o1[3]), pk2(o1[4], o1[5]), pk2(o1[6], o1[7])};
  uint4 w1 = {pk2(o1[8], o1[9]), pk2(o1[10], o1[11]), pk2(o1[12], o1[13]), pk2(o1[14], o1[15])};
  *(uint4*)&h[base + 4096] = w0;
  *(uint4*)&h[base + 4096 + 8] = w1;
}

// --------------- MFMA 1x1-conv GEMM (OC=256): Out[oc,p] = W[oc,:]@In[:,p]
__global__ __launch_bounds__(256) void k_gemm_mfma(
    const bf16* __restrict__ In, const float* __restrict__ W,
    const float* __restrict__ bias,
    const float* __restrict__ bng, const float* __restrict__ bnb,
    const float* __restrict__ bnm, const float* __restrict__ bnv,
    int has_bn, int relu,
    bf16* __restrict__ Out, int IC) {
  __shared__ __align__(16) bf16 Al[128][40];
  __shared__ __align__(16) bf16 Bl[64][40];

  int t = threadIdx.x;
  int w = t >> 6, lane = t & 63, l16 = lane & 15, quad = lane >> 4;
  int wr = w >> 1, wc = w & 1;
  int p0 = blockIdx.x * 64;
  int oc0 = blockIdx.y * 128;
  int b = blockIdx.z;
  const bf16* Inb = In + (size_t)b * IC * 4096;

  f32x4 acc[4][2];
#pragma unroll
  for (int mi = 0; mi < 4; mi++)
#pragma unroll
    for (int nj = 0; nj < 2; nj++) acc[mi][nj] = (f32x4){0.f, 0.f, 0.f, 0.f};

  int sl = t & 15, srp = t >> 4;
  int ocl = t >> 1, kb = (t & 1) * 16;

  for (int kc = 0; kc < IC; kc += 32) {
    __syncthreads();
    {
      const float* src = W + (size_t)(oc0 + ocl) * IC + kc + kb;
      float4 f0 = *(const float4*)(src);
      float4 f1 = *(const float4*)(src + 4);
      float4 f2 = *(const float4*)(src + 8);
      float4 f3 = *(const float4*)(src + 12);
      uint4 u0 = {pk2(f0.x, f0.y), pk2(f0.z, f0.w), pk2(f1.x, f1.y), pk2(f1.z, f1.w)};
      uint4 u1 = {pk2(f2.x, f2.y), pk2(f2.z, f2.w), pk2(f3.x, f3.y), pk2(f3.z, f3.w)};
      *(uint4*)&Al[ocl][kb] = u0;
      *(uint4*)&Al[ocl][kb + 8] = u1;
    }
    {
      const unsigned short* re = (const unsigned short*)(Inb + (size_t)(kc + 2 * srp) * 4096 + p0 + sl);
#pragma unroll
      for (int j = 0; j < 4; j++) {
        unsigned int e = re[j * 16];
        unsigned int o = re[4096 + j * 16];
        *(unsigned int*)&Bl[j * 16 + sl][2 * srp] = e | (o << 16);
      }
    }
    __syncthreads();
    bf16x8 af[4], bv[2];
#pragma unroll
    for (int mi = 0; mi < 4; mi++)
      af[mi] = *(const bf16x8*)&Al[wr * 64 + mi * 16 + l16][quad * 8];
#pragma unroll
    for (int nj = 0; nj < 2; nj++)
      bv[nj] = *(const bf16x8*)&Bl[wc * 32 + nj * 16 + l16][quad * 8];
#pragma unroll
    for (int mi = 0; mi < 4; mi++)
#pragma unroll
      for (int nj = 0; nj < 2; nj++)
        acc[mi][nj] = __builtin_amdgcn_mfma_f32_16x16x32_bf16(
            af[mi], bv[nj], acc[mi][nj], 0, 0, 0);
  }

#pragma unroll
  for (int mi = 0; mi < 4; mi++) {
    int ocb = oc0 + wr * 64 + mi * 16 + quad * 4;
    float4 bs4 = *(const float4*)&bias[ocb];
    float4 sc4 = {1.f, 1.f, 1.f, 1.f}, sh4 = bs4;
    if (has_bn) {
      float4 g4 = *(const float4*)&bng[ocb];
      float4 b4 = *(const float4*)&bnb[ocb];
      float4 m4 = *(const float4*)&bnm[ocb];
      float4 v4 = *(const float4*)&bnv[ocb];
      sc4.x = g4.x * rsqrtf(v4.x + EPSB); sh4.x = bs4.x * sc4.x + b4.x - m4.x * sc4.x;
      sc4.y = g4.y * rsqrtf(v4.y + EPSB); sh4.y = bs4.y * sc4.y + b4.y - m4.y * sc4.y;
      sc4.z = g4.z * rsqrtf(v4.z + EPSB); sh4.z = bs4.z * sc4.z + b4.z - m4.z * sc4.z;
      sc4.w = g4.w * rsqrtf(v4.w + EPSB); sh4.w = bs4.w * sc4.w + b4.w - m4.w * sc4.w;
    }
    float sc[4] = {sc4.x, sc4.y, sc4.z, sc4.w};
    float sh[4] = {sh4.x, sh4.y, sh4.z, sh4.w};
#pragma unroll
    for (int nj = 0; nj < 2; nj++) {
      int p = p0 + wc * 32 + nj * 16 + l16;
#pragma unroll
      for (int r = 0; r < 4; r++) {
        float val = acc[mi][nj][r] * sc[r] + sh[r];
        if (relu) val = fmaxf(val, 0.f);
        Out[(((size_t)(b * 256 + ocb + r)) << 12) + p] = __float2bfloat16(val);
      }
    }
  }
}

// ---------------- MFMA q/k GEMM (OC=32, IC=256), q & k fused via blockIdx.y
__global__ __launch_bounds__(256) void k_gemm_qk(
    const bf16* __restrict__ x4, const bf16* __restrict__ x3,
    const float* __restrict__ wq, const float* __restrict__ wk,
    const float* __restrict__ bq, const float* __restrict__ bk,
    bf16* __restrict__ qb, bf16* __restrict__ kb) {
  __shared__ __align__(16) bf16 Al[32][40];
  __shared__ __align__(16) bf16 Bl[128][40];

  int t = threadIdx.x;
  int w = t >> 6, lane = t & 63, l16 = lane & 15, quad = lane >> 4;
  int p0 = blockIdx.x * 128;
  int b = blockIdx.z;
  const bf16* In  = (blockIdx.y == 0) ? x4 : x3;
  const float* W  = (blockIdx.y == 0) ? wq : wk;
  const float* bi = (blockIdx.y == 0) ? bq : bk;
  bf16* Out       = (blockIdx.y == 0) ? qb : kb;
  const bf16* Inb = In + (size_t)b * 256 * 4096;

  f32x4 acc[2][2];
#pragma unroll
  for (int mi = 0; mi < 2; mi++)
#pragma unroll
    for (int nj = 0; nj < 2; nj++) acc[mi][nj] = (f32x4){0.f, 0.f, 0.f, 0.f};

  int aocl = t >> 3, akb = (t & 7) * 4;
  int sl = t & 15, srp = t >> 4;

  for (int kc = 0; kc < 256; kc += 32) {
    __syncthreads();
    {
      const float* src = W + (size_t)aocl * 256 + kc + akb;
      float4 f0 = *(const float4*)(src);
      uint2 u = {pk2(f0.x, f0.y), pk2(f0.z, f0.w)};
      *(uint2*)&Al[aocl][akb] = u;
    }
    {
      const unsigned short* re = (const unsigned short*)(Inb + (size_t)(kc + 2 * srp) * 4096 + p0 + sl);
#pragma unroll
      for (int j = 0; j < 8; j++) {
        unsigned int e = re[j * 16];
        unsigned int o = re[4096 + j * 16];
        *(unsigned int*)&Bl[j * 16 + sl][2 * srp] = e | (o << 16);
      }
    }
    __syncthreads();
    bf16x8 af[2], bv[2];
#pragma unroll
    for (int mi = 0; mi < 2; mi++)
      af[mi] = *(const bf16x8*)&Al[mi * 16 + l16][quad * 8];
#pragma unroll
    for (int nj = 0; nj < 2; nj++)
      bv[nj] = *(const bf16x8*)&Bl[w * 32 + nj * 16 + l16][quad * 8];
#pragma unroll
    for (int mi = 0; mi < 2; mi++)
#pragma unroll
      for (int nj = 0; nj < 2; nj++)
        acc[mi][nj] = __builtin_amdgcn_mfma_f32_16x16x32_bf16(
            af[mi], bv[nj], acc[mi][nj], 0, 0, 0);
  }

#pragma unroll
  for (int mi = 0; mi < 2; mi++) {
    int ocb = mi * 16 + quad * 4;
    float4 bs4 = *(const float4*)&bi[ocb];
    float bs[4] = {bs4.x, bs4.y, bs4.z, bs4.w};
#pragma unroll
    for (int nj = 0; nj < 2; nj++) {
      int p = p0 + w * 32 + nj * 16 + l16;
      float v0 = acc[mi][nj][0] + bs[0];
      float v1 = acc[mi][nj][1] + bs[1];
      float v2 = acc[mi][nj][2] + bs[2];
      float v3 = acc[mi][nj][3] + bs[3];
      uint2 u = {pk2(v0, v1), pk2(v2, v3)};
      *(uint2*)&Out[((size_t)(b * 4096) + p) * 32 + ocb] = u;
    }
  }
}

// ------------------------------------------- MFMA flash attention + residual
// v5: BARRIER-FREE K-loop. Block = 32 q x 128 c (chalf), 8 waves split the
// 4096 keys (512 each) and free-run. S^T = K.Q^T leaves P in the exact
// register layout needed as PV's B-operand (k-slots quad*8+j, j<4) of a
// zero-padded 16x16x32 MFMA -- P never touches LDS. Cross-wave key-reduction
// of acc happens once at the end via a 16.5 KB LDS chunk loop.
// Grid flat 1024, XCD-swizzled: xcd=id&7 -> batch=xcd>>1 (L2 locality).
__global__ __launch_bounds__(512, 4) void k_attn_mfma(
    const bf16* __restrict__ qb, const bf16* __restrict__ kb,
    const bf16* __restrict__ vb, const float* __restrict__ x1,
    const float* __restrict__ gamma, float* __restrict__ out) {
  const int R = 64 * 8 + 4;           // wave region stride (floats), pad 4
  __shared__ float part[8 * R];       // 16.5 KB
  __shared__ float lsumw[8][32];

  int id = blockIdx.x;
  int xcd = id & 7;
  int b = xcd >> 1;
  int sub = ((id >> 3) << 1) | (xcd & 1);   // 0..255
  int q0 = (sub >> 1) * 32;
  int chalf = sub & 1;

  int t = threadIdx.x;
  int w = t >> 6, lane = t & 63;
  int l16 = lane & 15, quad = lane >> 4;

  const bf16* kbb = kb + (size_t)b * 4096 * 32;
  const bf16* vbb = vb + (size_t)b * 256 * 4096 + (size_t)chalf * 128 * 4096;

  // Q B-frags (n=l16 -> q=q0+qt*16+l16, k=quad*8+j over d=32)
  bf16x8 qf[2];
#pragma unroll
  for (int qt = 0; qt < 2; qt++)
    qf[qt] = *(const bf16x8*)(qb + ((size_t)(b * 4096 + q0 + qt * 16 + l16)) * 32 + quad * 8);

  f32x4 acc[8][2];
#pragma unroll
  for (int ct = 0; ct < 8; ct++)
#pragma unroll
    for (int qt = 0; qt < 2; qt++) acc[ct][qt] = (f32x4){0.f, 0.f, 0.f, 0.f};
  float lp[2] = {0.f, 0.f};

  int kw0 = w * 512;                                    // this wave's key base
  const bf16* kp = kbb + ((size_t)(kw0 + l16)) * 32 + quad * 8;
  const bf16* vp = vbb + (size_t)l16 * 4096 + kw0 + quad * 4;

  for (int s = 0; s < 32; s++) {
    int ko = s * 16;
    bf16x8 kf = *(const bf16x8*)(kp + (size_t)ko * 32);
    uint2 lv[8];
#pragma unroll
    for (int ct = 0; ct < 8; ct++)
      lv[ct] = *(const uint2*)(vp + (size_t)ct * 16 * 4096 + ko);

    // S^T: lane -> P[key=kw0+ko+quad*4+r][q=q0+qt*16+l16]
    bf16x8 pf[2];
#pragma unroll
    for (int qt = 0; qt < 2; qt++) {
      f32x4 d1 = __builtin_amdgcn_mfma_f32_16x16x32_bf16(
          kf, qf[qt], (f32x4){0.f, 0.f, 0.f, 0.f}, 0, 0, 0);
      float p0f = __expf(fminf(d1[0], 80.f));
      float p1f = __expf(fminf(d1[1], 80.f));
      float p2f = __expf(fminf(d1[2], 80.f));
      float p3f = __expf(fminf(d1[3], 80.f));
      lp[qt] += (p0f + p1f) + (p2f + p3f);
      u4h8 pu;
      pu.u = (uint4){pk2(p0f, p1f), pk2(p2f, p3f), 0u, 0u};
      pf[qt] = pu.h;
    }
    // PV (zero-padded K=32 acting as K=16): acc[c][q] += V[c][k]*P[k][q]
#pragma unroll
    for (int ct = 0; ct < 8; ct++) {
      u4h8 vu;
      vu.u = (uint4){lv[ct].x, lv[ct].y, 0u, 0u};
#pragma unroll
      for (int qt = 0; qt < 2; qt++)
        acc[ct][qt] = __builtin_amdgcn_mfma_f32_16x16x32_bf16(
            vu.h, pf[qt], acc[ct][qt], 0, 0, 0);
    }
  }

  // denominators: reduce over quads, publish per wave
#pragma unroll
  for (int qt = 0; qt < 2; qt++) {
    float v = lp[qt];
    v += __shfl_xor(v, 16);
    v += __shfl_xor(v, 32);
    lp[qt] = v;
  }
  if (lane < 16) {
    lsumw[w][lane] = lp[0];
    lsumw[w][16 + lane] = lp[1];
  }
  __syncthreads();

  // reducer identity: qlocal = t&31 (q), cg = t>>5 (c-subtile)
  int qlocal = t & 31, cg = t >> 5;
  int l16q = qlocal & 15, qt_r = qlocal >> 4;
  int qd = cg >> 2, rr = cg & 3;
  int vsel = qt_r * 4 + rr;
  int srcidx = (qd * 16 + l16q) * 8 + vsel;
  float ls = 0.f;
#pragma unroll
  for (int w8 = 0; w8 < 8; w8++) ls += lsumw[w8][qt_r * 16 + l16q];
  float gl = gamma[0] / ls;
  int qg = q0 + qt_r * 16 + l16q;

  for (int ct = 0; ct < 8; ct++) {
    __syncthreads();
    {
      float* pw = part + w * R + lane * 8;
      *(float4*)pw = *(float4*)&acc[ct][0];
      *(float4*)(pw + 4) = *(float4*)&acc[ct][1];
    }
    __syncthreads();
    float sum = 0.f;
#pragma unroll
    for (int w8 = 0; w8 < 8; w8++) sum += part[w8 * R + srcidx];
    int c = chalf * 128 + ct * 16 + qd * 4 + rr;
    size_t gi = (((size_t)(b * 256 + c)) << 12) + qg;
    out[gi] = gl * sum + x1[gi];
  }
}

// ------------------------------------------------------------------- launcher
extern "C" void kernel_launch(void* const* d_in, const int* in_sizes, int n_in,
                              void* d_out, int out_size, void* d_ws, size_t ws_size,
                              hipStream_t stream) {
  const float* x1    = (const float*)d_in[0];
  const float* x2    = (const float*)d_in[1];
  const float* w1_dw = (const float*)d_in[2];
  const float* b1_dw = (const float*)d_in[3];
  const float* w1_pw = (const float*)d_in[4];
  const float* b1_pw = (const float*)d_in[5];
  const float* bn1_g = (const float*)d_in[6];
  const float* bn1_b = (const float*)d_in[7];
  const float* bn1_m = (const float*)d_in[8];
  const float* bn1_v = (const float*)d_in[9];
  const float* w2_dw = (const float*)d_in[10];
  const float* b2_dw = (const float*)d_in[11];
  const float* w2_pw = (const float*)d_in[12];
  const float* b2_pw = (const float*)d_in[13];
  const float* bn2_g = (const float*)d_in[14];
  const float* bn2_b = (const float*)d_in[15];
  const float* bn2_m = (const float*)d_in[16];
  const float* bn2_v = (const float*)d_in[17];
  const float* wq    = (const float*)d_in[18];
  const float* bq    = (const float*)d_in[19];
  const float* wk    = (const float*)d_in[20];
  const float* bk    = (const float*)d_in[21];
  const float* wv    = (const float*)d_in[22];
  const float* bv    = (const float*)d_in[23];
  const float* gamma = (const float*)d_in[24];

  // ws layout (bf16 units): h 8.4M | x3 4.2M | x4 4.2M | qb .5M | kb .5M | v 4.2M
  bf16* wsb = (bf16*)d_ws;
  bf16* h   = wsb;
  bf16* x3  = wsb + 8388608;
  bf16* x4  = wsb + 12582912;
  bf16* qbf = wsb + 16777216;
  bf16* kbf = wsb + 17301504;
  bf16* vvb = wsb + 17825792;

  k_dwconv2<<<dim3(256, 4), 256, 0, stream>>>(x1, x2, x1, w1_dw, b1_dw, h);
  k_gemm_mfma<<<dim3(64, 2, 4), 256, 0, stream>>>(h, w1_pw, b1_pw, bn1_g, bn1_b,
                                                  bn1_m, bn1_v, 1, 1, x3, 512);
  k_dwconv2<<<dim3(256, 4), 256, 0, stream>>>(x1, x2, x2, w2_dw, b2_dw, h);
  k_gemm_mfma<<<dim3(64, 2, 4), 256, 0, stream>>>(h, w2_pw, b2_pw, bn2_g, bn2_b,
                                                  bn2_m, bn2_v, 1, 1, x4, 512);

  k_gemm_qk<<<dim3(32, 2, 4), 256, 0, stream>>>(x4, x3, wq, wk, bq, bk, qbf, kbf);
  k_gemm_mfma<<<dim3(64, 2, 4), 256, 0, stream>>>(x3, wv, bv, nullptr, nullptr,
                                                  nullptr, nullptr, 0, 0, vvb, 256);

  k_attn_mfma<<<dim3(1024), 512, 0, stream>>>(qbf, kbf, vvb, x1, gamma, (float*)d_out);
}

// Round 9
// 283.037 us; speedup vs baseline: 1.7012x; 1.7012x over previous
//
#include <hip/hip_runtime.h>
#include <hip/hip_bf16.h>

#define EPSB 1e-5f

typedef __hip_bfloat16 bf16;
typedef __attribute__((ext_vector_type(8))) short bf16x8;
typedef __attribute__((ext_vector_type(4))) float f32x4;

__device__ __forceinline__ unsigned short f2bu(float x) {
  bf16 h = __float2bfloat16(x);
  return *reinterpret_cast<unsigned short*>(&h);
}
__device__ __forceinline__ unsigned int pk2(float lo, float hi) {
  return ((unsigned int)f2bu(hi) << 16) | (unsigned int)f2bu(lo);
}

// ---------------- fused dual grouped 3x3 conv (both blocks), bf16 outputs
// block = (g 0..255, batch). g<128: input pair = (x1-x2)[2g,2g+1], used for
// BOTH h1 (w1) and h2 (w2). g>=128: h1 from x1 pair with w1, h2 from x2 pair
// with w2 (restaged). x1/x2 each read exactly once per launch.
__global__ __launch_bounds__(256) void k_dwconv3(
    const float* __restrict__ x1, const float* __restrict__ x2,
    const float* __restrict__ w1, const float* __restrict__ b1,
    const float* __restrict__ w2, const float* __restrict__ b2,
    bf16* __restrict__ h1, bf16* __restrict__ h2) {
  __shared__ float img[2 * 64 * 64];
  int g = blockIdx.x, b = blockIdx.y;
  int t = threadIdx.x;
  int row = t >> 2, x0 = (t & 3) * 16;
  size_t obase = (((size_t)(b * 512 + 2 * g)) << 12) + row * 64 + x0;

  auto stencil = [&](const float* wp, float bs0, float bs1, bf16* hout) {
    float o0[16], o1[16];
#pragma unroll
    for (int i = 0; i < 16; i++) { o0[i] = bs0; o1[i] = bs1; }
#pragma unroll
    for (int ch = 0; ch < 2; ch++) {
      float wa[9], wb[9];
#pragma unroll
      for (int i = 0; i < 9; i++) { wa[i] = wp[ch * 9 + i]; wb[i] = wp[18 + ch * 9 + i]; }
      const float* ib = img + ch * 4096;
#pragma unroll
      for (int ky = 0; ky < 3; ky++) {
        int yy = row + ky - 1;
        if (yy < 0 || yy > 63) continue;
        float v[18];
#pragma unroll
        for (int c = 0; c < 18; c++) {
          int xx = x0 + c - 1;
          v[c] = (xx >= 0 && xx < 64) ? ib[yy * 64 + xx] : 0.f;
        }
        float a0 = wa[ky * 3], a1 = wa[ky * 3 + 1], a2 = wa[ky * 3 + 2];
        float c0 = wb[ky * 3], c1 = wb[ky * 3 + 1], c2 = wb[ky * 3 + 2];
#pragma unroll
        for (int i = 0; i < 16; i++) {
          o0[i] += a0 * v[i] + a1 * v[i + 1] + a2 * v[i + 2];
          o1[i] += c0 * v[i] + c1 * v[i + 1] + c2 * v[i + 2];
        }
      }
    }
    uint4 u0 = {pk2(o0[0], o0[1]), pk2(o0[2], o0[3]), pk2(o0[4], o0[5]), pk2(o0[6], o0[7])};
    uint4 u1 = {pk2(o0[8], o0[9]), pk2(o0[10], o0[11]), pk2(o0[12], o0[13]), pk2(o0[14], o0[15])};
    *(uint4*)&hout[obase] = u0;
    *(uint4*)&hout[obase + 8] = u1;
    uint4 w0 = {pk2(o1[0], o1[1]), pk2(o1[2], o1[3]), pk2(o1[4], o1[5]), pk2(o1[6], o1[7])};
    uint4 w1v = {pk2(o1[8], o1[9]), pk2(o1[10], o1[11]), pk2(o1[12], o1[13]), pk2(o1[14], o1[15])};
    *(uint4*)&hout[obase + 4096] = w0;
    *(uint4*)&hout[obase + 4096 + 8] = w1v;
  };

  // stage pass-A input
  if (g < 128) {
    const float4* p1 = (const float4*)(x1 + ((size_t)(b * 256 + 2 * g) << 12));
    const float4* p2 = (const float4*)(x2 + ((size_t)(b * 256 + 2 * g) << 12));
#pragma unroll
    for (int u = 0; u < 8; u++) {
      int i = u * 256 + t;
      float4 a = p1[i], c = p2[i];
      float4 d = {a.x - c.x, a.y - c.y, a.z - c.z, a.w - c.w};
      ((float4*)img)[i] = d;
    }
  } else {
    const float4* p1 = (const float4*)(x1 + ((size_t)(b * 256 + 2 * (g - 128)) << 12));
#pragma unroll
    for (int u = 0; u < 8; u++) {
      int i = u * 256 + t;
      ((float4*)img)[i] = p1[i];
    }
  }
  __syncthreads();
  stencil(w1 + (size_t)(2 * g) * 18, b1[2 * g], b1[2 * g + 1], h1);

  if (g >= 128) {   // restage with x2 pair (block-uniform branch)
    __syncthreads();
    const float4* p2 = (const float4*)(x2 + ((size_t)(b * 256 + 2 * (g - 128)) << 12));
#pragma unroll
    for (int u = 0; u < 8; u++) {
      int i = u * 256 + t;
      ((float4*)img)[i] = p2[i];
    }
    __syncthreads();
  }
  stencil(w2 + (size_t)(2 * g) * 18, b2[2 * g], b2[2 * g + 1], h2);
}

// --------------- MFMA 1x1-conv GEMM (OC=256): Out[oc,p] = W[oc,:]@In[:,p]
__global__ __launch_bounds__(256) void k_gemm_mfma(
    const bf16* __restrict__ In, const float* __restrict__ W,
    const float* __restrict__ bias,
    const float* __restrict__ bng, const float* __restrict__ bnb,
    const float* __restrict__ bnm, const float* __restrict__ bnv,
    int has_bn, int relu,
    bf16* __restrict__ Out, int IC) {
  __shared__ __align__(16) bf16 Al[128][40];
  __shared__ __align__(16) bf16 Bl[64][40];

  int t = threadIdx.x;
  int w = t >> 6, lane = t & 63, l16 = lane & 15, quad = lane >> 4;
  int wr = w >> 1, wc = w & 1;
  int p0 = blockIdx.x * 64;
  int oc0 = blockIdx.y * 128;
  int b = blockIdx.z;
  const bf16* Inb = In + (size_t)b * IC * 4096;

  f32x4 acc[4][2];
#pragma unroll
  for (int mi = 0; mi < 4; mi++)
#pragma unroll
    for (int nj = 0; nj < 2; nj++) acc[mi][nj] = (f32x4){0.f, 0.f, 0.f, 0.f};

  int sl = t & 15, srp = t >> 4;
  int ocl = t >> 1, kb = (t & 1) * 16;

  for (int kc = 0; kc < IC; kc += 32) {
    __syncthreads();
    {
      const float* src = W + (size_t)(oc0 + ocl) * IC + kc + kb;
      float4 f0 = *(const float4*)(src);
      float4 f1 = *(const float4*)(src + 4);
      float4 f2 = *(const float4*)(src + 8);
      float4 f3 = *(const float4*)(src + 12);
      uint4 u0 = {pk2(f0.x, f0.y), pk2(f0.z, f0.w), pk2(f1.x, f1.y), pk2(f1.z, f1.w)};
      uint4 u1 = {pk2(f2.x, f2.y), pk2(f2.z, f2.w), pk2(f3.x, f3.y), pk2(f3.z, f3.w)};
      *(uint4*)&Al[ocl][kb] = u0;
      *(uint4*)&Al[ocl][kb + 8] = u1;
    }
    {
      const unsigned short* re = (const unsigned short*)(Inb + (size_t)(kc + 2 * srp) * 4096 + p0 + sl);
#pragma unroll
      for (int j = 0; j < 4; j++) {
        unsigned int e = re[j * 16];
        unsigned int o = re[4096 + j * 16];
        *(unsigned int*)&Bl[j * 16 + sl][2 * srp] = e | (o << 16);
      }
    }
    __syncthreads();
    bf16x8 af[4], bv[2];
#pragma unroll
    for (int mi = 0; mi < 4; mi++)
      af[mi] = *(const bf16x8*)&Al[wr * 64 + mi * 16 + l16][quad * 8];
#pragma unroll
    for (int nj = 0; nj < 2; nj++)
      bv[nj] = *(const bf16x8*)&Bl[wc * 32 + nj * 16 + l16][quad * 8];
#pragma unroll
    for (int mi = 0; mi < 4; mi++)
#pragma unroll
      for (int nj = 0; nj < 2; nj++)
        acc[mi][nj] = __builtin_amdgcn_mfma_f32_16x16x32_bf16(
            af[mi], bv[nj], acc[mi][nj], 0, 0, 0);
  }

#pragma unroll
  for (int mi = 0; mi < 4; mi++) {
    int ocb = oc0 + wr * 64 + mi * 16 + quad * 4;
    float4 bs4 = *(const float4*)&bias[ocb];
    float4 sc4 = {1.f, 1.f, 1.f, 1.f}, sh4 = bs4;
    if (has_bn) {
      float4 g4 = *(const float4*)&bng[ocb];
      float4 b4 = *(const float4*)&bnb[ocb];
      float4 m4 = *(const float4*)&bnm[ocb];
      float4 v4 = *(const float4*)&bnv[ocb];
      sc4.x = g4.x * rsqrtf(v4.x + EPSB); sh4.x = bs4.x * sc4.x + b4.x - m4.x * sc4.x;
      sc4.y = g4.y * rsqrtf(v4.y + EPSB); sh4.y = bs4.y * sc4.y + b4.y - m4.y * sc4.y;
      sc4.z = g4.z * rsqrtf(v4.z + EPSB); sh4.z = bs4.z * sc4.z + b4.z - m4.z * sc4.z;
      sc4.w = g4.w * rsqrtf(v4.w + EPSB); sh4.w = bs4.w * sc4.w + b4.w - m4.w * sc4.w;
    }
    float sc[4] = {sc4.x, sc4.y, sc4.z, sc4.w};
    float sh[4] = {sh4.x, sh4.y, sh4.z, sh4.w};
#pragma unroll
    for (int nj = 0; nj < 2; nj++) {
      int p = p0 + wc * 32 + nj * 16 + l16;
#pragma unroll
      for (int r = 0; r < 4; r++) {
        float val = acc[mi][nj][r] * sc[r] + sh[r];
        if (relu) val = fmaxf(val, 0.f);
        Out[(((size_t)(b * 256 + ocb + r)) << 12) + p] = __float2bfloat16(val);
      }
    }
  }
}

// ---------------- MFMA q/k GEMM (OC=32, IC=256), q & k fused via blockIdx.y
__global__ __launch_bounds__(256) void k_gemm_qk(
    const bf16* __restrict__ x4, const bf16* __restrict__ x3,
    const float* __restrict__ wq, const float* __restrict__ wk,
    const float* __restrict__ bq, const float* __restrict__ bk,
    bf16* __restrict__ qb, bf16* __restrict__ kb) {
  __shared__ __align__(16) bf16 Al[32][40];
  __shared__ __align__(16) bf16 Bl[128][40];

  int t = threadIdx.x;
  int w = t >> 6, lane = t & 63, l16 = lane & 15, quad = lane >> 4;
  int p0 = blockIdx.x * 128;
  int b = blockIdx.z;
  const bf16* In  = (blockIdx.y == 0) ? x4 : x3;
  const float* W  = (blockIdx.y == 0) ? wq : wk;
  const float* bi = (blockIdx.y == 0) ? bq : bk;
  bf16* Out       = (blockIdx.y == 0) ? qb : kb;
  const bf16* Inb = In + (size_t)b * 256 * 4096;

  f32x4 acc[2][2];
#pragma unroll
  for (int mi = 0; mi < 2; mi++)
#pragma unroll
    for (int nj = 0; nj < 2; nj++) acc[mi][nj] = (f32x4){0.f, 0.f, 0.f, 0.f};

  int aocl = t >> 3, akb = (t & 7) * 4;
  int sl = t & 15, srp = t >> 4;

  for (int kc = 0; kc < 256; kc += 32) {
    __syncthreads();
    {
      const float* src = W + (size_t)aocl * 256 + kc + akb;
      float4 f0 = *(const float4*)(src);
      uint2 u = {pk2(f0.x, f0.y), pk2(f0.z, f0.w)};
      *(uint2*)&Al[aocl][akb] = u;
    }
    {
      const unsigned short* re = (const unsigned short*)(Inb + (size_t)(kc + 2 * srp) * 4096 + p0 + sl);
#pragma unroll
      for (int j = 0; j < 8; j++) {
        unsigned int e = re[j * 16];
        unsigned int o = re[4096 + j * 16];
        *(unsigned int*)&Bl[j * 16 + sl][2 * srp] = e | (o << 16);
      }
    }
    __syncthreads();
    bf16x8 af[2], bv[2];
#pragma unroll
    for (int mi = 0; mi < 2; mi++)
      af[mi] = *(const bf16x8*)&Al[mi * 16 + l16][quad * 8];
#pragma unroll
    for (int nj = 0; nj < 2; nj++)
      bv[nj] = *(const bf16x8*)&Bl[w * 32 + nj * 16 + l16][quad * 8];
#pragma unroll
    for (int mi = 0; mi < 2; mi++)
#pragma unroll
      for (int nj = 0; nj < 2; nj++)
        acc[mi][nj] = __builtin_amdgcn_mfma_f32_16x16x32_bf16(
            af[mi], bv[nj], acc[mi][nj], 0, 0, 0);
  }

#pragma unroll
  for (int mi = 0; mi < 2; mi++) {
    int ocb = mi * 16 + quad * 4;
    float4 bs4 = *(const float4*)&bi[ocb];
    float bs[4] = {bs4.x, bs4.y, bs4.z, bs4.w};
#pragma unroll
    for (int nj = 0; nj < 2; nj++) {
      int p = p0 + w * 32 + nj * 16 + l16;
      float v0 = acc[mi][nj][0] + bs[0];
      float v1 = acc[mi][nj][1] + bs[1];
      float v2 = acc[mi][nj][2] + bs[2];
      float v3 = acc[mi][nj][3] + bs[3];
      uint2 u = {pk2(v0, v1), pk2(v2, v3)};
      *(uint2*)&Out[((size_t)(b * 4096) + p) * 32 + ocb] = u;
    }
  }
}

// ------------------------------------------- MFMA flash attention + residual
// v6 = v3 pipeline + channel split. Block = 64 q x 128 c (chalf); grid
// (128,B) = 512 blocks = 2/CU so co-resident blocks fill each other's
// barrier drains. 128-key iters, one barrier per phase, double-buffered P.
// S: wave w owns keys w*16..+16 for all 64 q. PV: wave w owns 16 channels.
__global__ __launch_bounds__(512, 4) void k_attn_mfma(
    const bf16* __restrict__ qb, const bf16* __restrict__ kb,
    const bf16* __restrict__ vb, const float* __restrict__ x1,
    const float* __restrict__ gamma, float* __restrict__ out) {
  __shared__ __align__(16) bf16 Pl[2][64 * 128];   // 32 KB
  __shared__ float lsumw[8][64];

  int t = threadIdx.x;
  int w = t >> 6, lane = t & 63;
  int l16 = lane & 15, quad = lane >> 4;
  int bx = blockIdx.x;
  int q0 = (bx >> 1) * 64;
  int chalf = bx & 1;
  int b = blockIdx.y;

  const bf16* kbb = kb + (size_t)b * 4096 * 32;
  const bf16* vbb = vb + ((size_t)(b * 256 + chalf * 128)) * 4096;

  bf16x8 qf[4];
#pragma unroll
  for (int nj = 0; nj < 4; nj++)
    qf[nj] = *(const bf16x8*)(qb + ((size_t)(b * 4096 + q0 + nj * 16 + l16)) * 32 + quad * 8);

  f32x4 acc[4];
#pragma unroll
  for (int nj = 0; nj < 4; nj++) acc[nj] = (f32x4){0.f, 0.f, 0.f, 0.f};
  float lpart[4] = {0.f, 0.f, 0.f, 0.f};

  const bf16* kptr = kbb + ((size_t)(w * 16 + l16)) * 32 + quad * 8;
  const bf16* vptr = vbb + ((size_t)(w * 16 + l16)) * 4096 + quad * 8;

  int c16w = w * 2 + (quad >> 1);
  int off8 = (quad & 1) * 4;

  auto load_kv = [&](int j0, bf16x8& kf, bf16x8 vf[4]) {
    kf = *(const bf16x8*)(kptr + (size_t)j0 * 32);
#pragma unroll
    for (int kc = 0; kc < 4; kc++)
      vf[kc] = *(const bf16x8*)(vptr + j0 + kc * 32);
  };

  auto s_phase = [&](const bf16x8& kf, int pb) {
    bf16* P = Pl[pb];
#pragma unroll
    for (int nj = 0; nj < 4; nj++) {
      f32x4 s = __builtin_amdgcn_mfma_f32_16x16x32_bf16(
          kf, qf[nj], (f32x4){0.f, 0.f, 0.f, 0.f}, 0, 0, 0);
      float p0f = __expf(fminf(s[0], 80.f));
      float p1f = __expf(fminf(s[1], 80.f));
      float p2f = __expf(fminf(s[2], 80.f));
      float p3f = __expf(fminf(s[3], 80.f));
      lpart[nj] += (p0f + p1f) + (p2f + p3f);
      int row = nj * 16 + l16;
      int c16 = c16w ^ (row & 15);
      uint2 u = {pk2(p0f, p1f), pk2(p2f, p3f)};
      *(uint2*)&P[row * 128 + c16 * 8 + off8] = u;
    }
  };

  auto pv_phase = [&](const bf16x8 vf[4], int pb) {
    const bf16* P = Pl[pb];
#pragma unroll
    for (int kc = 0; kc < 4; kc++) {
      bf16x8 pf[4];
#pragma unroll
      for (int nj = 0; nj < 4; nj++) {
        int row = nj * 16 + l16;
        int c16 = (kc * 4 + quad) ^ (row & 15);
        pf[nj] = *(const bf16x8*)&P[row * 128 + c16 * 8];
      }
#pragma unroll
      for (int nj = 0; nj < 4; nj++)
        acc[nj] = __builtin_amdgcn_mfma_f32_16x16x32_bf16(
            vf[kc], pf[nj], acc[nj], 0, 0, 0);
    }
  };

  bf16x8 kfA, kfB, vfA[4], vfB[4];
  load_kv(0, kfA, vfA);
  s_phase(kfA, 0);

  for (int i = 0; i < 32; i += 2) {
    __syncthreads();
    if (i < 31) load_kv((i + 1) * 128, kfB, vfB);
    pv_phase(vfA, 0);
    if (i < 31) s_phase(kfB, 1);
    __syncthreads();
    if (i + 2 < 32) load_kv((i + 2) * 128, kfA, vfA);
    if (i + 1 < 32) pv_phase(vfB, 1);
    if (i + 2 < 32) s_phase(kfA, 0);
  }

#pragma unroll
  for (int nj = 0; nj < 4; nj++) {
    float v = lpart[nj];
    v += __shfl_xor(v, 16);
    v += __shfl_xor(v, 32);
    lpart[nj] = v;
  }
  if (lane < 16) {
#pragma unroll
    for (int nj = 0; nj < 4; nj++) lsumw[w][nj * 16 + lane] = lpart[nj];
  }
  __syncthreads();

  float gm = gamma[0];
#pragma unroll
  for (int nj = 0; nj < 4; nj++) {
    int ql = nj * 16 + l16;
    float ls = 0.f;
#pragma unroll
    for (int w8 = 0; w8 < 8; w8++) ls += lsumw[w8][ql];
    float gl = gm / ls;
    int cb = chalf * 128 + w * 16 + quad * 4;
#pragma unroll
    for (int r = 0; r < 4; r++) {
      size_t gidx = (((size_t)(b * 256 + cb + r)) << 12) + q0 + ql;
      out[gidx] = gl * acc[nj][r] + x1[gidx];
    }
  }
}

// ------------------------------------------------------------------- launcher
extern "C" void kernel_launch(void* const* d_in, const int* in_sizes, int n_in,
                              void* d_out, int out_size, void* d_ws, size_t ws_size,
                              hipStream_t stream) {
  const float* x1    = (const float*)d_in[0];
  const float* x2    = (const float*)d_in[1];
  const float* w1_dw = (const float*)d_in[2];
  const float* b1_dw = (const float*)d_in[3];
  const float* w1_pw = (const float*)d_in[4];
  const float* b1_pw = (const float*)d_in[5];
  const float* bn1_g = (const float*)d_in[6];
  const float* bn1_b = (const float*)d_in[7];
  const float* bn1_m = (const float*)d_in[8];
  const float* bn1_v = (const float*)d_in[9];
  const float* w2_dw = (const float*)d_in[10];
  const float* b2_dw = (const float*)d_in[11];
  const float* w2_pw = (const float*)d_in[12];
  const float* b2_pw = (const float*)d_in[13];
  const float* bn2_g = (const float*)d_in[14];
  const float* bn2_b = (const float*)d_in[15];
  const float* bn2_m = (const float*)d_in[16];
  const float* bn2_v = (const float*)d_in[17];
  const float* wq    = (const float*)d_in[18];
  const float* bq    = (const float*)d_in[19];
  const float* wk    = (const float*)d_in[20];
  const float* bk    = (const float*)d_in[21];
  const float* wv    = (const float*)d_in[22];
  const float* bv    = (const float*)d_in[23];
  const float* gamma = (const float*)d_in[24];

  // ws layout (bf16 units): h1 8.4M | h2 8.4M | x3 4.2M | x4 4.2M |
  // qb .5M | kb .5M | v 4.2M  -> 30.4M elems = 60.8 MB
  bf16* wsb = (bf16*)d_ws;
  bf16* h1  = wsb;
  bf16* h2  = wsb + 8388608;
  bf16* x3  = wsb + 16777216;
  bf16* x4  = wsb + 20971520;
  bf16* qbf = wsb + 25165824;
  bf16* kbf = wsb + 25690112;
  bf16* vvb = wsb + 26214400;

  k_dwconv3<<<dim3(256, 4), 256, 0, stream>>>(x1, x2, w1_dw, b1_dw, w2_dw, b2_dw, h1, h2);
  k_gemm_mfma<<<dim3(64, 2, 4), 256, 0, stream>>>(h1, w1_pw, b1_pw, bn1_g, bn1_b,
                                                  bn1_m, bn1_v, 1, 1, x3, 512);
  k_gemm_mfma<<<dim3(64, 2, 4), 256, 0, stream>>>(h2, w2_pw, b2_pw, bn2_g, bn2_b,
                                                  bn2_m, bn2_v, 1, 1, x4, 512);

  k_gemm_qk<<<dim3(32, 2, 4), 256, 0, stream>>>(x4, x3, wq, wk, bq, bk, qbf, kbf);
  k_gemm_mfma<<<dim3(64, 2, 4), 256, 0, stream>>>(x3, wv, bv, nullptr, nullptr,
                                                  nullptr, nullptr, 0, 0, vvb, 256);

  k_attn_mfma<<<dim3(128, 4), 512, 0, stream>>>(qbf, kbf, vvb, x1, gamma, (float*)d_out);
}